// Round 1
// baseline (519.249 us; speedup 1.0000x reference)
//
#include <hip/hip_runtime.h>
#include <math.h>

#define N_NODES  50000
#define N_EDGES  600000
#define IN_SIZE  128
#define HIDDEN   256
#define OUT_SIZE 128
#define NB_SCAN  ((N_NODES + 255) / 256)   // 196

// ---------------- CSR build ----------------
__global__ void k_zero_deg(int* __restrict__ deg) {
  int i = blockIdx.x * 256 + threadIdx.x;
  if (i < N_NODES) deg[i] = 0;
}

__global__ void k_count(const int* __restrict__ dst, int* __restrict__ deg) {
  int i = blockIdx.x * 256 + threadIdx.x;
  if (i < N_EDGES) atomicAdd(&deg[dst[i]], 1);
}

__global__ void k_scanA(const int* __restrict__ deg, int* __restrict__ partial,
                        int* __restrict__ blockSums) {
  __shared__ int s[256];
  int t = threadIdx.x;
  int i = blockIdx.x * 256 + t;
  int v = (i < N_NODES) ? deg[i] : 0;
  s[t] = v; __syncthreads();
  for (int off = 1; off < 256; off <<= 1) {
    int y = (t >= off) ? s[t - off] : 0;
    __syncthreads();
    s[t] += y;
    __syncthreads();
  }
  if (i < N_NODES) partial[i] = s[t] - v;   // exclusive within block
  if (t == 255) blockSums[blockIdx.x] = s[255];
}

__global__ void k_scanB(int* __restrict__ blockSums, int nb) {
  __shared__ int s[256];
  int t = threadIdx.x;
  int v = (t < nb) ? blockSums[t] : 0;
  s[t] = v; __syncthreads();
  for (int off = 1; off < 256; off <<= 1) {
    int y = (t >= off) ? s[t - off] : 0;
    __syncthreads();
    s[t] += y;
    __syncthreads();
  }
  if (t < nb) blockSums[t] = s[t] - v;      // exclusive block offsets
}

__global__ void k_scanC(int* __restrict__ rowStart, const int* __restrict__ blockSums,
                        int* __restrict__ cursor) {
  int i = blockIdx.x * 256 + threadIdx.x;
  if (i < N_NODES) {
    int r = rowStart[i] + blockSums[blockIdx.x];
    rowStart[i] = r;
    cursor[i] = r;
  }
}

__global__ void k_fill(const int* __restrict__ src, const int* __restrict__ dst,
                       int* __restrict__ cursor, int* __restrict__ col) {
  int i = blockIdx.x * 256 + threadIdx.x;
  if (i < N_EDGES) {
    int p = atomicAdd(&cursor[dst[i]], 1);
    col[p] = src[i];
  }
}

// ---------------- gather-mean aggregation ----------------
// one wave per node; 128 dims -> float2 per lane
__global__ void k_agg1(const float* __restrict__ x, const int* __restrict__ rowStart,
                       const int* __restrict__ deg, const int* __restrict__ col,
                       float* __restrict__ agg) {
  int waveId = threadIdx.x >> 6, lane = threadIdx.x & 63;
  int n = blockIdx.x * 4 + waveId;
  if (n >= N_NODES) return;
  int rs = rowStart[n], dg = deg[n];
  int d0 = lane * 2;
  float a0 = 0.f, a1 = 0.f;
  for (int j = 0; j < dg; ++j) {
    int s = col[rs + j];
    float2 v = *(const float2*)(x + (size_t)s * IN_SIZE + d0);
    a0 += v.x; a1 += v.y;
  }
  float inv = 1.0f / fmaxf((float)dg, 1.0f);
  float2 o; o.x = a0 * inv; o.y = a1 * inv;
  *(float2*)(agg + (size_t)n * IN_SIZE + d0) = o;
}

// one wave per node; 256 dims -> float4 per lane
__global__ void k_agg2(const float* __restrict__ x, const int* __restrict__ rowStart,
                       const int* __restrict__ deg, const int* __restrict__ col,
                       float* __restrict__ agg) {
  int waveId = threadIdx.x >> 6, lane = threadIdx.x & 63;
  int n = blockIdx.x * 4 + waveId;
  if (n >= N_NODES) return;
  int rs = rowStart[n], dg = deg[n];
  int d0 = lane * 4;
  float a0 = 0.f, a1 = 0.f, a2 = 0.f, a3 = 0.f;
  for (int j = 0; j < dg; ++j) {
    int s = col[rs + j];
    float4 v = *(const float4*)(x + (size_t)s * HIDDEN + d0);
    a0 += v.x; a1 += v.y; a2 += v.z; a3 += v.w;
  }
  float inv = 1.0f / fmaxf((float)dg, 1.0f);
  float4 o; o.x = a0 * inv; o.y = a1 * inv; o.z = a2 * inv; o.w = a3 * inv;
  *(float4*)(agg + (size_t)n * HIDDEN + d0) = o;
}

// ---------------- layer 1 GEMM: h1 = relu(normalize([agg|x] @ Wcat.T + b1)) ----------------
// block tile: 32 nodes x 256 outs; 256 threads; thread = 4 nodes x 8 outs
__global__ __launch_bounds__(256) void k_gemm1(
    const float* __restrict__ agg, const float* __restrict__ feat,
    const float* __restrict__ W1l, const float* __restrict__ W1r,
    const float* __restrict__ b1, float* __restrict__ h1) {
  __shared__ float w_s[32][256];   // [kk][out]
  __shared__ float in_s[32][40];   // [kk][node], stride 40 keeps float4 alignment
  __shared__ float red_s[32][33];
  __shared__ float inv_s[32];
  __shared__ float b_s[256];
  const int t = threadIdx.x;
  const int tx = t & 31, ny = t >> 5;
  const int nodeBase = blockIdx.x * 32;
  b_s[t] = b1[t];
  float acc[4][8] = {};
  const int ldNode = t >> 3;
  const int ldKK = (t & 7) * 4;
  const int gnLd = min(nodeBase + ldNode, N_NODES - 1);

  for (int c = 0; c < 8; ++c) {
    const float* Wsrc = (c < 4) ? W1l : W1r;
    const float* Xsrc = (c < 4) ? agg : feat;
    const int k0 = (c & 3) * 32;
    {
      const float* wp = Wsrc + t * IN_SIZE + k0;   // out = t
      #pragma unroll
      for (int j = 0; j < 8; ++j) {
        float4 v = *(const float4*)(wp + j * 4);
        w_s[j * 4 + 0][t] = v.x; w_s[j * 4 + 1][t] = v.y;
        w_s[j * 4 + 2][t] = v.z; w_s[j * 4 + 3][t] = v.w;
      }
    }
    {
      float4 v = *(const float4*)(Xsrc + (size_t)gnLd * IN_SIZE + k0 + ldKK);
      in_s[ldKK + 0][ldNode] = v.x; in_s[ldKK + 1][ldNode] = v.y;
      in_s[ldKK + 2][ldNode] = v.z; in_s[ldKK + 3][ldNode] = v.w;
    }
    __syncthreads();
    #pragma unroll 8
    for (int kk = 0; kk < 32; ++kk) {
      float4 xi = *(const float4*)&in_s[kk][ny * 4];
      float4 wa = *(const float4*)&w_s[kk][tx * 4];
      float4 wb = *(const float4*)&w_s[kk][128 + tx * 4];
      float xv[4] = {xi.x, xi.y, xi.z, xi.w};
      float wv[8] = {wa.x, wa.y, wa.z, wa.w, wb.x, wb.y, wb.z, wb.w};
      #pragma unroll
      for (int i = 0; i < 4; ++i)
        #pragma unroll
        for (int j = 0; j < 8; ++j)
          acc[i][j] = fmaf(xv[i], wv[j], acc[i][j]);
    }
    __syncthreads();
  }
  // epilogue: bias, row L2-norm, relu, store
  #pragma unroll
  for (int i = 0; i < 4; ++i) {
    #pragma unroll
    for (int j = 0; j < 8; ++j) {
      int out = (j < 4) ? (tx * 4 + j) : (128 + tx * 4 + (j - 4));
      acc[i][j] += b_s[out];
    }
  }
  #pragma unroll
  for (int i = 0; i < 4; ++i) {
    float ss = 0.f;
    #pragma unroll
    for (int j = 0; j < 8; ++j) ss += acc[i][j] * acc[i][j];
    red_s[ny * 4 + i][tx] = ss;
  }
  __syncthreads();
  if (t < 32) {
    float s = 0.f;
    #pragma unroll
    for (int j = 0; j < 32; ++j) s += red_s[t][j];
    inv_s[t] = 1.0f / fmaxf(sqrtf(s), 1e-12f);
  }
  __syncthreads();
  #pragma unroll
  for (int i = 0; i < 4; ++i) {
    int node = ny * 4 + i, gn = nodeBase + node;
    if (gn < N_NODES) {
      float iv = inv_s[node];
      float4 o1, o2;
      o1.x = fmaxf(acc[i][0] * iv, 0.f); o1.y = fmaxf(acc[i][1] * iv, 0.f);
      o1.z = fmaxf(acc[i][2] * iv, 0.f); o1.w = fmaxf(acc[i][3] * iv, 0.f);
      o2.x = fmaxf(acc[i][4] * iv, 0.f); o2.y = fmaxf(acc[i][5] * iv, 0.f);
      o2.z = fmaxf(acc[i][6] * iv, 0.f); o2.w = fmaxf(acc[i][7] * iv, 0.f);
      *(float4*)(h1 + (size_t)gn * HIDDEN + tx * 4) = o1;
      *(float4*)(h1 + (size_t)gn * HIDDEN + 128 + tx * 4) = o2;
    }
  }
}

// ---------------- layer 2 GEMM + fc + softmax ----------------
// block tile: 32 nodes x 128 outs; thread = 4 nodes x 4 outs; K = 512 (agg2|h1)
__global__ __launch_bounds__(256) void k_gemm2(
    const float* __restrict__ agg, const float* __restrict__ h1,
    const float* __restrict__ W2l, const float* __restrict__ W2r,
    const float* __restrict__ b2, const float* __restrict__ Wfc,
    const float* __restrict__ bfc, float* __restrict__ out) {
  __shared__ float w_s[32][128];
  __shared__ float in_s[32][40];
  __shared__ float red_s[32][33];
  __shared__ float inv_s[32];
  __shared__ float l0_s[32];
  __shared__ float b_s[128];
  __shared__ float wfc_s[256];
  const int t = threadIdx.x;
  const int tx = t & 31, ny = t >> 5;
  const int nodeBase = blockIdx.x * 32;
  if (t < 128) b_s[t] = b2[t];
  wfc_s[t] = Wfc[t];
  float acc[4][4] = {};
  const int ldNode = t >> 3;
  const int ldKK = (t & 7) * 4;
  const int gnLd = min(nodeBase + ldNode, N_NODES - 1);
  const int wOut = t & 127, wKH = (t >> 7) * 16;

  for (int c = 0; c < 16; ++c) {
    const float* Wsrc = (c < 8) ? W2l : W2r;
    const float* Xsrc = (c < 8) ? agg : h1;
    const int k0 = (c & 7) * 32;
    {
      const float* wp = Wsrc + wOut * HIDDEN + k0 + wKH;
      #pragma unroll
      for (int j = 0; j < 4; ++j) {
        float4 v = *(const float4*)(wp + j * 4);
        w_s[wKH + j * 4 + 0][wOut] = v.x; w_s[wKH + j * 4 + 1][wOut] = v.y;
        w_s[wKH + j * 4 + 2][wOut] = v.z; w_s[wKH + j * 4 + 3][wOut] = v.w;
      }
    }
    {
      float4 v = *(const float4*)(Xsrc + (size_t)gnLd * HIDDEN + k0 + ldKK);
      in_s[ldKK + 0][ldNode] = v.x; in_s[ldKK + 1][ldNode] = v.y;
      in_s[ldKK + 2][ldNode] = v.z; in_s[ldKK + 3][ldNode] = v.w;
    }
    __syncthreads();
    #pragma unroll 8
    for (int kk = 0; kk < 32; ++kk) {
      float4 xi = *(const float4*)&in_s[kk][ny * 4];
      float4 wq = *(const float4*)&w_s[kk][tx * 4];
      float xv[4] = {xi.x, xi.y, xi.z, xi.w};
      float wv[4] = {wq.x, wq.y, wq.z, wq.w};
      #pragma unroll
      for (int i = 0; i < 4; ++i)
        #pragma unroll
        for (int j = 0; j < 4; ++j)
          acc[i][j] = fmaf(xv[i], wv[j], acc[i][j]);
    }
    __syncthreads();
  }
  // bias
  #pragma unroll
  for (int i = 0; i < 4; ++i)
    #pragma unroll
    for (int j = 0; j < 4; ++j)
      acc[i][j] += b_s[tx * 4 + j];
  // row sum-of-squares
  #pragma unroll
  for (int i = 0; i < 4; ++i) {
    float ss = 0.f;
    #pragma unroll
    for (int j = 0; j < 4; ++j) ss += acc[i][j] * acc[i][j];
    red_s[ny * 4 + i][tx] = ss;
  }
  __syncthreads();
  if (t < 32) {
    float s = 0.f;
    #pragma unroll
    for (int j = 0; j < 32; ++j) s += red_s[t][j];
    inv_s[t] = 1.0f / fmaxf(sqrtf(s), 1e-12f);
  }
  __syncthreads();
  // fc partials: logits[c] = sum_j h[j] * Wfc[c][j]
  float p0[4], p1[4];
  #pragma unroll
  for (int i = 0; i < 4; ++i) {
    float iv = inv_s[ny * 4 + i];
    float s0 = 0.f, s1 = 0.f;
    #pragma unroll
    for (int j = 0; j < 4; ++j) {
      float h = acc[i][j] * iv;
      s0 += h * wfc_s[tx * 4 + j];
      s1 += h * wfc_s[128 + tx * 4 + j];
    }
    p0[i] = s0; p1[i] = s1;
  }
  #pragma unroll
  for (int i = 0; i < 4; ++i) red_s[ny * 4 + i][tx] = p0[i];
  __syncthreads();
  if (t < 32) {
    float s = 0.f;
    #pragma unroll
    for (int j = 0; j < 32; ++j) s += red_s[t][j];
    l0_s[t] = s;
  }
  __syncthreads();
  #pragma unroll
  for (int i = 0; i < 4; ++i) red_s[ny * 4 + i][tx] = p1[i];
  __syncthreads();
  if (t < 32) {
    float l1 = 0.f;
    #pragma unroll
    for (int j = 0; j < 32; ++j) l1 += red_s[t][j];
    float l0 = l0_s[t] + bfc[0];
    l1 += bfc[1];
    float m = fmaxf(l0, l1);
    float e0 = expf(l0 - m), e1 = expf(l1 - m);
    float inv = 1.0f / (e0 + e1);
    int gn = nodeBase + t;
    if (gn < N_NODES) {
      out[(size_t)gn * 2 + 0] = e0 * inv;
      out[(size_t)gn * 2 + 1] = e1 * inv;
    }
  }
}

extern "C" void kernel_launch(void* const* d_in, const int* in_sizes, int n_in,
                              void* d_out, int out_size, void* d_ws, size_t ws_size,
                              hipStream_t stream) {
  const float* feat = (const float*)d_in[0];
  const int* eidx = (const int*)d_in[1];
  const int* src = eidx;
  const int* dst = eidx + N_EDGES;
  const float* W1l = (const float*)d_in[2];
  const float* b1  = (const float*)d_in[3];
  const float* W1r = (const float*)d_in[4];
  const float* W2l = (const float*)d_in[5];
  const float* b2  = (const float*)d_in[6];
  const float* W2r = (const float*)d_in[7];
  const float* Wfc = (const float*)d_in[8];
  const float* bfc = (const float*)d_in[9];
  float* out = (float*)d_out;

  // workspace layout (16B-aligned chunks)
  int* deg       = (int*)d_ws;
  int* rowStart  = deg + 50176;
  int* cursor    = rowStart + 50176;
  int* blockSums = cursor + 50176;
  int* col       = blockSums + 256;
  float* agg1    = (float*)(col + 600064);
  float* h1      = agg1 + (size_t)N_NODES * IN_SIZE;
  float* agg2    = h1 + (size_t)N_NODES * HIDDEN;

  k_zero_deg<<<NB_SCAN, 256, 0, stream>>>(deg);
  k_count<<<(N_EDGES + 255) / 256, 256, 0, stream>>>(dst, deg);
  k_scanA<<<NB_SCAN, 256, 0, stream>>>(deg, rowStart, blockSums);
  k_scanB<<<1, 256, 0, stream>>>(blockSums, NB_SCAN);
  k_scanC<<<NB_SCAN, 256, 0, stream>>>(rowStart, blockSums, cursor);
  k_fill<<<(N_EDGES + 255) / 256, 256, 0, stream>>>(src, dst, cursor, col);
  k_agg1<<<N_NODES / 4, 256, 0, stream>>>(feat, rowStart, deg, col, agg1);
  k_gemm1<<<(N_NODES + 31) / 32, 256, 0, stream>>>(agg1, feat, W1l, W1r, b1, h1);
  k_agg2<<<N_NODES / 4, 256, 0, stream>>>(h1, rowStart, deg, col, agg2);
  k_gemm2<<<(N_NODES + 31) / 32, 256, 0, stream>>>(agg2, h1, W2l, W2r, b2, Wfc, bfc, out);
}

// Round 2
// 441.436 us; speedup vs baseline: 1.1763x; 1.1763x over previous
//
#include <hip/hip_runtime.h>
#include <math.h>

#define N_NODES  50000
#define N_EDGES  600000
#define IN_SIZE  128
#define HIDDEN   256
#define OUT_SIZE 128
#define NB_SCAN  ((N_NODES + 255) / 256)   // 196

typedef __attribute__((ext_vector_type(8))) short bf16x8;
typedef __attribute__((ext_vector_type(4))) float f32x4;
typedef unsigned int uint32;

__device__ __forceinline__ unsigned short f2bf(float x) {
  uint32 u = __builtin_bit_cast(uint32, x);
  u += 0x7FFFu + ((u >> 16) & 1u);   // round-to-nearest-even
  return (unsigned short)(u >> 16);
}
__device__ __forceinline__ float bf2f(uint32 lo16) {
  return __builtin_bit_cast(float, lo16 << 16);
}

// ---------------- CSR build ----------------
__global__ void k_zero_deg(int* __restrict__ deg) {
  int i = blockIdx.x * 256 + threadIdx.x;
  if (i < N_NODES) deg[i] = 0;
}

__global__ void k_count(const int* __restrict__ dst, int* __restrict__ deg) {
  int i = blockIdx.x * 256 + threadIdx.x;
  if (i < N_EDGES) atomicAdd(&deg[dst[i]], 1);
}

__global__ void k_scanA(const int* __restrict__ deg, int* __restrict__ partial,
                        int* __restrict__ blockSums) {
  __shared__ int s[256];
  int t = threadIdx.x;
  int i = blockIdx.x * 256 + t;
  int v = (i < N_NODES) ? deg[i] : 0;
  s[t] = v; __syncthreads();
  for (int off = 1; off < 256; off <<= 1) {
    int y = (t >= off) ? s[t - off] : 0;
    __syncthreads();
    s[t] += y;
    __syncthreads();
  }
  if (i < N_NODES) partial[i] = s[t] - v;
  if (t == 255) blockSums[blockIdx.x] = s[255];
}

__global__ void k_scanB(int* __restrict__ blockSums, int nb) {
  __shared__ int s[256];
  int t = threadIdx.x;
  int v = (t < nb) ? blockSums[t] : 0;
  s[t] = v; __syncthreads();
  for (int off = 1; off < 256; off <<= 1) {
    int y = (t >= off) ? s[t - off] : 0;
    __syncthreads();
    s[t] += y;
    __syncthreads();
  }
  if (t < nb) blockSums[t] = s[t] - v;
}

__global__ void k_scanC(int* __restrict__ rowStart, const int* __restrict__ blockSums,
                        int* __restrict__ cursor) {
  int i = blockIdx.x * 256 + threadIdx.x;
  if (i < N_NODES) {
    int r = rowStart[i] + blockSums[blockIdx.x];
    rowStart[i] = r;
    cursor[i] = r;
  }
}

__global__ void k_fill(const int* __restrict__ src, const int* __restrict__ dst,
                       int* __restrict__ cursor, int* __restrict__ col) {
  int i = blockIdx.x * 256 + threadIdx.x;
  if (i < N_EDGES) {
    int p = atomicAdd(&cursor[dst[i]], 1);
    col[p] = src[i];
  }
}

// ---------------- f32 -> bf16 conversions ----------------
__global__ void k_cvt(const float* __restrict__ x, unsigned short* __restrict__ y, int n2) {
  int i = blockIdx.x * 256 + threadIdx.x;   // 2 elements per thread
  if (i < n2) {
    float2 v = ((const float2*)x)[i];
    ((uint32*)y)[i] = (uint32)f2bf(v.x) | ((uint32)f2bf(v.y) << 16);
  }
}

// Wc1[n][k], n=0..255 output neuron, k<128 -> W1l[n][k], else W1r[n][k-128]
__global__ void k_cvtw1(const float* __restrict__ W1l, const float* __restrict__ W1r,
                        unsigned short* __restrict__ Wc) {
  int id = blockIdx.x * 256 + threadIdx.x;   // 65536
  int n = id >> 8, k = id & 255;
  float v = (k < 128) ? W1l[n * 128 + k] : W1r[n * 128 + (k - 128)];
  Wc[id] = f2bf(v);
}

// Wc2[n][k], n<128 -> W2l[n][k] (Tl outs), n>=128 -> W2r[n-128][k] (Tr outs); k over 256 h1 dims
__global__ void k_cvtw2(const float* __restrict__ W2l, const float* __restrict__ W2r,
                        unsigned short* __restrict__ Wc) {
  int id = blockIdx.x * 256 + threadIdx.x;   // 65536
  int n = id >> 8, k = id & 255;
  float v = (n < 128) ? W2l[n * 256 + k] : W2r[(n - 128) * 256 + k];
  Wc[id] = f2bf(v);
}

// ---------------- gather-mean over bf16 feat rows (128 dims) ----------------
// one wave per node; lane holds dims {2*lane, 2*lane+1}
__global__ void k_agg1(const unsigned short* __restrict__ x, const int* __restrict__ rowStart,
                       const int* __restrict__ deg, const int* __restrict__ col,
                       unsigned short* __restrict__ agg) {
  int lane = threadIdx.x & 63;
  int n = blockIdx.x * 4 + (threadIdx.x >> 6);
  int rs = rowStart[n], dg = deg[n];
  const uint32* base = (const uint32*)x;   // row stride = 64 uints
  float s0 = 0.f, s1 = 0.f;
  for (int j = 0; j < dg; ++j) {
    int s = col[rs + j];
    uint32 v = base[(size_t)s * 64 + lane];
    s0 += bf2f(v & 0xffffu); s1 += bf2f(v >> 16);
  }
  float inv = 1.0f / fmaxf((float)dg, 1.0f);
  uint32 o = (uint32)f2bf(s0 * inv) | ((uint32)f2bf(s1 * inv) << 16);
  ((uint32*)agg)[(size_t)n * 64 + lane] = o;
}

// ---------------- MFMA GEMM: Y(bf16)[M][256] = [A0|A1](bf16, K=256) @ W(bf16,[256][256])^T ----------------
// wave handles 16 rows x 256 cols; 16 acc frags; no LDS.
// NORM: +bias, row-L2-normalize, relu (layer 1). else raw store (layer 2).
template<bool NORM>
__global__ __launch_bounds__(256) void k_mfma(
    const unsigned short* __restrict__ A0, const unsigned short* __restrict__ A1, int lda,
    const unsigned short* __restrict__ W, const float* __restrict__ bias,
    unsigned short* __restrict__ Y) {
  const int lane = threadIdx.x & 63;
  const int w = threadIdx.x >> 6;
  const int m0 = blockIdx.x * 64 + w * 16;
  if (m0 >= N_NODES) return;            // 50000 % 16 == 0: waves fully valid or fully idle
  const int mi = lane & 15, quad = lane >> 4;
  const unsigned short* a0p = A0 + (size_t)(m0 + mi) * lda + quad * 8;
  const unsigned short* a1p = A1 + (size_t)(m0 + mi) * lda + quad * 8;
  const unsigned short* bp  = W + (size_t)mi * 256 + quad * 8;
  f32x4 acc[16];
  #pragma unroll
  for (int nt = 0; nt < 16; ++nt) acc[nt] = (f32x4){0.f, 0.f, 0.f, 0.f};
  #pragma unroll
  for (int c = 0; c < 8; ++c) {
    const unsigned short* ap = (c < 4) ? (a0p + c * 32) : (a1p + (c - 4) * 32);
    bf16x8 a = *(const bf16x8*)ap;
    #pragma unroll
    for (int nt = 0; nt < 16; ++nt) {
      bf16x8 b = *(const bf16x8*)(bp + nt * (16 * 256) + c * 32);
      acc[nt] = __builtin_amdgcn_mfma_f32_16x16x32_bf16(a, b, acc[nt], 0, 0, 0);
    }
  }
  if (NORM) {
    #pragma unroll
    for (int nt = 0; nt < 16; ++nt) {
      float bv = bias[nt * 16 + mi];
      #pragma unroll
      for (int r = 0; r < 4; ++r) acc[nt][r] += bv;
    }
    float ss0 = 0.f, ss1 = 0.f, ss2 = 0.f, ss3 = 0.f;
    #pragma unroll
    for (int nt = 0; nt < 16; ++nt) {
      ss0 += acc[nt][0] * acc[nt][0];
      ss1 += acc[nt][1] * acc[nt][1];
      ss2 += acc[nt][2] * acc[nt][2];
      ss3 += acc[nt][3] * acc[nt][3];
    }
    // reduce across the 16 lanes sharing this quad (they hold the same 4 rows)
    #pragma unroll
    for (int m = 1; m < 16; m <<= 1) {
      ss0 += __shfl_xor(ss0, m, 64);
      ss1 += __shfl_xor(ss1, m, 64);
      ss2 += __shfl_xor(ss2, m, 64);
      ss3 += __shfl_xor(ss3, m, 64);
    }
    float iv0 = 1.0f / fmaxf(sqrtf(ss0), 1e-12f);
    float iv1 = 1.0f / fmaxf(sqrtf(ss1), 1e-12f);
    float iv2 = 1.0f / fmaxf(sqrtf(ss2), 1e-12f);
    float iv3 = 1.0f / fmaxf(sqrtf(ss3), 1e-12f);
    #pragma unroll
    for (int nt = 0; nt < 16; ++nt) {
      acc[nt][0] = fmaxf(acc[nt][0] * iv0, 0.f);
      acc[nt][1] = fmaxf(acc[nt][1] * iv1, 0.f);
      acc[nt][2] = fmaxf(acc[nt][2] * iv2, 0.f);
      acc[nt][3] = fmaxf(acc[nt][3] * iv3, 0.f);
    }
  }
  // store: row = m0 + quad*4 + r, col = nt*16 + mi
  #pragma unroll
  for (int nt = 0; nt < 16; ++nt) {
    #pragma unroll
    for (int r = 0; r < 4; ++r) {
      int row = m0 + quad * 4 + r;
      Y[(size_t)row * 256 + nt * 16 + mi] = f2bf(acc[nt][r]);
    }
  }
}

// ---------------- fused layer-2 tail: gather-mean Tl + Tr + b2, normalize, fc, softmax ----------------
// T[n][0:128]=Tl (to aggregate), T[n][128:256]=Tr. one wave per node; lane holds dims {2l,2l+1}
__global__ void k_final(const unsigned short* __restrict__ T, const int* __restrict__ rowStart,
                        const int* __restrict__ deg, const int* __restrict__ col,
                        const float* __restrict__ b2, const float* __restrict__ Wfc,
                        const float* __restrict__ bfc, float* __restrict__ out) {
  int lane = threadIdx.x & 63;
  int n = blockIdx.x * 4 + (threadIdx.x >> 6);
  int rs = rowStart[n], dg = deg[n];
  const uint32* base = (const uint32*)T;   // row stride = 128 uints; Tl first 64, Tr next 64
  float s0 = 0.f, s1 = 0.f;
  for (int j = 0; j < dg; ++j) {
    int s = col[rs + j];
    uint32 v = base[(size_t)s * 128 + lane];
    s0 += bf2f(v & 0xffffu); s1 += bf2f(v >> 16);
  }
  float inv = 1.0f / fmaxf((float)dg, 1.0f);
  uint32 tv = base[(size_t)n * 128 + 64 + lane];
  int d = lane * 2;
  float h0 = s0 * inv + bf2f(tv & 0xffffu) + b2[d];
  float h1 = s1 * inv + bf2f(tv >> 16) + b2[d + 1];
  float ss = h0 * h0 + h1 * h1;
  #pragma unroll
  for (int m = 1; m < 64; m <<= 1) ss += __shfl_xor(ss, m, 64);
  float iv = 1.0f / fmaxf(sqrtf(ss), 1e-12f);
  h0 *= iv; h1 *= iv;
  float p0 = h0 * Wfc[d] + h1 * Wfc[d + 1];
  float p1 = h0 * Wfc[128 + d] + h1 * Wfc[128 + d + 1];
  #pragma unroll
  for (int m = 1; m < 64; m <<= 1) {
    p0 += __shfl_xor(p0, m, 64);
    p1 += __shfl_xor(p1, m, 64);
  }
  if (lane == 0) {
    float l0 = p0 + bfc[0], l1 = p1 + bfc[1];
    float mx = fmaxf(l0, l1);
    float e0 = expf(l0 - mx), e1 = expf(l1 - mx);
    float s = 1.0f / (e0 + e1);
    out[(size_t)n * 2 + 0] = e0 * s;
    out[(size_t)n * 2 + 1] = e1 * s;
  }
}

extern "C" void kernel_launch(void* const* d_in, const int* in_sizes, int n_in,
                              void* d_out, int out_size, void* d_ws, size_t ws_size,
                              hipStream_t stream) {
  const float* feat = (const float*)d_in[0];
  const int* eidx = (const int*)d_in[1];
  const int* src = eidx;
  const int* dst = eidx + N_EDGES;
  const float* W1l = (const float*)d_in[2];
  const float* b1  = (const float*)d_in[3];
  const float* W1r = (const float*)d_in[4];
  const float* W2l = (const float*)d_in[5];
  const float* b2  = (const float*)d_in[6];
  const float* W2r = (const float*)d_in[7];
  const float* Wfc = (const float*)d_in[8];
  const float* bfc = (const float*)d_in[9];
  float* out = (float*)d_out;

  // workspace layout
  int* deg       = (int*)d_ws;
  int* rowStart  = deg + 50176;
  int* cursor    = rowStart + 50176;
  int* blockSums = cursor + 50176;
  int* col       = blockSums + 256;                       // 600064
  unsigned short* featb = (unsigned short*)(col + 600064); // 50000*128
  unsigned short* agg1b = featb + 6400000;                 // 50000*128
  unsigned short* h1b   = agg1b + 6400000;                 // 50000*256
  unsigned short* Tb    = h1b + 12800000;                  // 50000*256
  unsigned short* Wc1   = Tb + 12800000;                   // 256*256
  unsigned short* Wc2   = Wc1 + 65536;                     // 256*256

  k_zero_deg<<<NB_SCAN, 256, 0, stream>>>(deg);
  k_count<<<(N_EDGES + 255) / 256, 256, 0, stream>>>(dst, deg);
  k_scanA<<<NB_SCAN, 256, 0, stream>>>(deg, rowStart, blockSums);
  k_scanB<<<1, 256, 0, stream>>>(blockSums, NB_SCAN);
  k_scanC<<<NB_SCAN, 256, 0, stream>>>(rowStart, blockSums, cursor);
  k_fill<<<(N_EDGES + 255) / 256, 256, 0, stream>>>(src, dst, cursor, col);

  k_cvt<<<(3200000 + 255) / 256, 256, 0, stream>>>(feat, featb, 3200000);
  k_cvtw1<<<256, 256, 0, stream>>>(W1l, W1r, Wc1);
  k_cvtw2<<<256, 256, 0, stream>>>(W2l, W2r, Wc2);

  k_agg1<<<N_NODES / 4, 256, 0, stream>>>(featb, rowStart, deg, col, agg1b);
  k_mfma<true><<<(N_NODES + 63) / 64, 256, 0, stream>>>(agg1b, featb, 128, Wc1, b1, h1b);
  k_mfma<false><<<(N_NODES + 63) / 64, 256, 0, stream>>>(h1b, h1b + 128, 256, Wc2, nullptr, Tb);
  k_final<<<N_NODES / 4, 256, 0, stream>>>(Tb, rowStart, deg, col, b2, Wfc, bfc, out);
}

// Round 3
// 297.673 us; speedup vs baseline: 1.7444x; 1.4830x over previous
//
#include <hip/hip_runtime.h>
#include <math.h>

#define N_NODES  50000
#define N_EDGES  600000
#define NB_SCAN  ((N_NODES + 255) / 256)   // 196

typedef __attribute__((ext_vector_type(8))) short bf16x8;
typedef __attribute__((ext_vector_type(4))) float f32x4;
typedef unsigned int uint32;

__device__ __forceinline__ unsigned short f2bf(float x) {
  uint32 u = __builtin_bit_cast(uint32, x);
  u += 0x7FFFu + ((u >> 16) & 1u);   // round-to-nearest-even
  return (unsigned short)(u >> 16);
}
__device__ __forceinline__ float bf2f(uint32 lo16) {
  return __builtin_bit_cast(float, lo16 << 16);
}

// ---------------- CSR build ----------------
__global__ void k_zero_deg(int* __restrict__ deg) {
  int i = blockIdx.x * 256 + threadIdx.x;
  if (i < N_NODES) deg[i] = 0;
}

__global__ void k_count(const int* __restrict__ dst, int* __restrict__ deg) {
  int i = blockIdx.x * 256 + threadIdx.x;
  if (i < N_EDGES) atomicAdd(&deg[dst[i]], 1);
}

__global__ void k_scanA(const int* __restrict__ deg, int* __restrict__ partial,
                        int* __restrict__ blockSums) {
  __shared__ int s[256];
  int t = threadIdx.x;
  int i = blockIdx.x * 256 + t;
  int v = (i < N_NODES) ? deg[i] : 0;
  s[t] = v; __syncthreads();
  for (int off = 1; off < 256; off <<= 1) {
    int y = (t >= off) ? s[t - off] : 0;
    __syncthreads();
    s[t] += y;
    __syncthreads();
  }
  if (i < N_NODES) partial[i] = s[t] - v;
  if (t == 255) blockSums[blockIdx.x] = s[255];
}

__global__ void k_scanB(int* __restrict__ blockSums, int nb) {
  __shared__ int s[256];
  int t = threadIdx.x;
  int v = (t < nb) ? blockSums[t] : 0;
  s[t] = v; __syncthreads();
  for (int off = 1; off < 256; off <<= 1) {
    int y = (t >= off) ? s[t - off] : 0;
    __syncthreads();
    s[t] += y;
    __syncthreads();
  }
  if (t < nb) blockSums[t] = s[t] - v;
}

__global__ void k_scanC(int* __restrict__ rowStart, const int* __restrict__ blockSums,
                        int* __restrict__ cursor) {
  int i = blockIdx.x * 256 + threadIdx.x;
  if (i < N_NODES) {
    int r = rowStart[i] + blockSums[blockIdx.x];
    rowStart[i] = r;
    cursor[i] = r;
  }
}

__global__ void k_fill(const int* __restrict__ src, const int* __restrict__ dst,
                       int* __restrict__ cursor, int* __restrict__ col) {
  int i = blockIdx.x * 256 + threadIdx.x;
  if (i < N_EDGES) {
    int p = atomicAdd(&cursor[dst[i]], 1);
    col[p] = src[i];
  }
}

// ---------------- f32 -> bf16 conversions ----------------
__global__ void k_cvt(const float* __restrict__ x, unsigned short* __restrict__ y, int n2) {
  int i = blockIdx.x * 256 + threadIdx.x;   // 2 elements per thread
  if (i < n2) {
    float2 v = ((const float2*)x)[i];
    ((uint32*)y)[i] = (uint32)f2bf(v.x) | ((uint32)f2bf(v.y) << 16);
  }
}

__global__ void k_cvtw1(const float* __restrict__ W1l, const float* __restrict__ W1r,
                        unsigned short* __restrict__ Wc) {
  int id = blockIdx.x * 256 + threadIdx.x;   // 65536
  int n = id >> 8, k = id & 255;
  float v = (k < 128) ? W1l[n * 128 + k] : W1r[n * 128 + (k - 128)];
  Wc[id] = f2bf(v);
}

__global__ void k_cvtw2(const float* __restrict__ W2l, const float* __restrict__ W2r,
                        unsigned short* __restrict__ Wc) {
  int id = blockIdx.x * 256 + threadIdx.x;   // 65536
  int n = id >> 8, k = id & 255;
  float v = (n < 128) ? W2l[n * 256 + k] : W2r[(n - 128) * 256 + k];
  Wc[id] = f2bf(v);
}

// ---------------- gather-mean over bf16 feat rows (128 dims) ----------------
// one wave per node; lane holds dims {2*lane, 2*lane+1}; 2 rows in flight
__global__ void k_agg1(const unsigned short* __restrict__ x, const int* __restrict__ rowStart,
                       const int* __restrict__ deg, const int* __restrict__ col,
                       unsigned short* __restrict__ agg) {
  int lane = threadIdx.x & 63;
  int n = blockIdx.x * 4 + (threadIdx.x >> 6);
  int rs = rowStart[n], dg = deg[n];
  const uint32* base = (const uint32*)x;   // row stride = 64 uints
  float s0a = 0.f, s1a = 0.f, s0b = 0.f, s1b = 0.f;
  int sA = col[rs];         // col[] has 64 ints of slack past N_EDGES
  int sB = col[rs + 1];
  int j = 0;
  for (; j + 2 <= dg; j += 2) {
    uint32 vA = base[(size_t)sA * 64 + lane];
    uint32 vB = base[(size_t)sB * 64 + lane];
    sA = col[rs + j + 2];
    sB = col[rs + j + 3];
    s0a += bf2f(vA & 0xffffu); s1a += bf2f(vA >> 16);
    s0b += bf2f(vB & 0xffffu); s1b += bf2f(vB >> 16);
  }
  if (j < dg) {
    uint32 vA = base[(size_t)sA * 64 + lane];
    s0a += bf2f(vA & 0xffffu); s1a += bf2f(vA >> 16);
  }
  float s0 = s0a + s0b, s1 = s1a + s1b;
  float inv = 1.0f / fmaxf((float)dg, 1.0f);
  uint32 o = (uint32)f2bf(s0 * inv) | ((uint32)f2bf(s1 * inv) << 16);
  ((uint32*)agg)[(size_t)n * 64 + lane] = o;
}

// ---------------- MFMA GEMM with LDS-staged W ----------------
// Y(bf16)[M][256] = [A0|A1](bf16, K=256) @ W(bf16,[256][256])^T
// block = 256 thr = 4 waves; wave = 32 rows (2 rt) x 256 cols; 2 halves of W
// staged per 64KB via global_load_lds; LDS layout chunk-transposed [j][n] (16B units)
// so B-frag ds_read_b128 hits all 32 banks evenly.
template<bool NORM>
__global__ __launch_bounds__(256, 2) void k_gemm(
    const unsigned short* __restrict__ A0, const unsigned short* __restrict__ A1,
    int lda, const unsigned short* __restrict__ W, const float* __restrict__ bias,
    unsigned short* __restrict__ Y) {
  __shared__ unsigned short Ws[128 * 256];  // 64 KB
  const int t = threadIdx.x;
  const int lane = t & 63, w = t >> 6;
  const int mi = lane & 15, quad = lane >> 4;
  const int m0 = blockIdx.x * 128 + w * 32;
  f32x4 acc[2][16];
  #pragma unroll
  for (int rt = 0; rt < 2; ++rt)
    #pragma unroll
    for (int a = 0; a < 16; ++a) acc[rt][a] = (f32x4){0.f, 0.f, 0.f, 0.f};

  for (int half = 0; half < 2; ++half) {
    // stage W rows [half*128, half*128+128) into Ws as [j=kchunk][n] 16B chunks
    {
      const unsigned short* gb = W + (size_t)half * 128 * 256;
      #pragma unroll
      for (int i = 0; i < 16; ++i) {
        int chunk0 = (w * 16 + i) * 64;          // wave-uniform
        int j = chunk0 >> 7;
        int n0 = chunk0 & 127;
        const unsigned short* gp = gb + (size_t)(n0 + lane) * 256 + j * 8;
        unsigned short* lp = Ws + (size_t)chunk0 * 8;
        __builtin_amdgcn_global_load_lds(
            (const __attribute__((address_space(1))) void*)gp,
            (__attribute__((address_space(3))) void*)lp, 16, 0, 0);
      }
    }
    __syncthreads();
    #pragma unroll
    for (int c = 0; c < 8; ++c) {
      const unsigned short* ap = (c < 4) ? (A0 + c * 32) : (A1 + (c - 4) * 32);
      bf16x8 a0 = *(const bf16x8*)(ap + (size_t)(m0 + mi) * lda + quad * 8);
      bf16x8 a1 = *(const bf16x8*)(ap + (size_t)(m0 + 16 + mi) * lda + quad * 8);
      #pragma unroll
      for (int nt = 0; nt < 8; ++nt) {
        bf16x8 b = *(const bf16x8*)(Ws + ((size_t)(c * 4 + quad) * 128 + nt * 16 + mi) * 8);
        int a = half * 8 + nt;
        acc[0][a] = __builtin_amdgcn_mfma_f32_16x16x32_bf16(a0, b, acc[0][a], 0, 0, 0);
        acc[1][a] = __builtin_amdgcn_mfma_f32_16x16x32_bf16(a1, b, acc[1][a], 0, 0, 0);
      }
    }
    __syncthreads();   // before restaging Ws
  }

  if (NORM) {
    float ss[2][4] = {};
    #pragma unroll
    for (int a = 0; a < 16; ++a) {
      float bv = bias[a * 16 + mi];
      #pragma unroll
      for (int rt = 0; rt < 2; ++rt)
        #pragma unroll
        for (int r = 0; r < 4; ++r) {
          float v = acc[rt][a][r] + bv;
          acc[rt][a][r] = v;
          ss[rt][r] += v * v;
        }
    }
    #pragma unroll
    for (int rt = 0; rt < 2; ++rt)
      #pragma unroll
      for (int r = 0; r < 4; ++r) {
        float s = ss[rt][r];
        s += __shfl_xor(s, 1, 64);
        s += __shfl_xor(s, 2, 64);
        s += __shfl_xor(s, 4, 64);
        s += __shfl_xor(s, 8, 64);
        ss[rt][r] = 1.0f / fmaxf(sqrtf(s), 1e-12f);
      }
    #pragma unroll
    for (int a = 0; a < 16; ++a)
      #pragma unroll
      for (int rt = 0; rt < 2; ++rt)
        #pragma unroll
        for (int r = 0; r < 4; ++r)
          acc[rt][a][r] = fmaxf(acc[rt][a][r] * ss[rt][r], 0.f);
  }

  if (m0 + 32 <= N_NODES) {
    #pragma unroll
    for (int rt = 0; rt < 2; ++rt)
      #pragma unroll
      for (int r = 0; r < 4; ++r) {
        size_t row = m0 + rt * 16 + quad * 4 + r;
        #pragma unroll
        for (int a = 0; a < 16; ++a)
          Y[row * 256 + a * 16 + mi] = f2bf(acc[rt][a][r]);
      }
  } else {
    #pragma unroll
    for (int rt = 0; rt < 2; ++rt)
      #pragma unroll
      for (int r = 0; r < 4; ++r) {
        int row = m0 + rt * 16 + quad * 4 + r;
        if (row < N_NODES) {
          #pragma unroll
          for (int a = 0; a < 16; ++a)
            Y[(size_t)row * 256 + a * 16 + mi] = f2bf(acc[rt][a][r]);
        }
      }
  }
}

// ---------------- fused layer-2 tail: gather-mean Tl + Tr + b2, normalize, fc, softmax ----------------
// T[n][0:128]=Tl (aggregated), T[n][128:256]=Tr. one wave per node; lane holds dims {2l,2l+1}
__global__ void k_final(const unsigned short* __restrict__ T, const int* __restrict__ rowStart,
                        const int* __restrict__ deg, const int* __restrict__ col,
                        const float* __restrict__ b2, const float* __restrict__ Wfc,
                        const float* __restrict__ bfc, float* __restrict__ out) {
  int lane = threadIdx.x & 63;
  int n = blockIdx.x * 4 + (threadIdx.x >> 6);
  int rs = rowStart[n], dg = deg[n];
  const uint32* base = (const uint32*)T;   // row stride = 128 uints; Tl first 64, Tr next 64
  float s0a = 0.f, s1a = 0.f, s0b = 0.f, s1b = 0.f;
  int sA = col[rs];
  int sB = col[rs + 1];
  int j = 0;
  for (; j + 2 <= dg; j += 2) {
    uint32 vA = base[(size_t)sA * 128 + lane];
    uint32 vB = base[(size_t)sB * 128 + lane];
    sA = col[rs + j + 2];
    sB = col[rs + j + 3];
    s0a += bf2f(vA & 0xffffu); s1a += bf2f(vA >> 16);
    s0b += bf2f(vB & 0xffffu); s1b += bf2f(vB >> 16);
  }
  if (j < dg) {
    uint32 vA = base[(size_t)sA * 128 + lane];
    s0a += bf2f(vA & 0xffffu); s1a += bf2f(vA >> 16);
  }
  float s0 = s0a + s0b, s1 = s1a + s1b;
  float inv = 1.0f / fmaxf((float)dg, 1.0f);
  uint32 tv = base[(size_t)n * 128 + 64 + lane];
  int d = lane * 2;
  float h0 = s0 * inv + bf2f(tv & 0xffffu) + b2[d];
  float h1 = s1 * inv + bf2f(tv >> 16) + b2[d + 1];
  float ss = h0 * h0 + h1 * h1;
  #pragma unroll
  for (int m = 1; m < 64; m <<= 1) ss += __shfl_xor(ss, m, 64);
  float iv = 1.0f / fmaxf(sqrtf(ss), 1e-12f);
  h0 *= iv; h1 *= iv;
  float p0 = h0 * Wfc[d] + h1 * Wfc[d + 1];
  float p1 = h0 * Wfc[128 + d] + h1 * Wfc[128 + d + 1];
  #pragma unroll
  for (int m = 1; m < 64; m <<= 1) {
    p0 += __shfl_xor(p0, m, 64);
    p1 += __shfl_xor(p1, m, 64);
  }
  if (lane == 0) {
    float l0 = p0 + bfc[0], l1 = p1 + bfc[1];
    float mx = fmaxf(l0, l1);
    float e0 = expf(l0 - mx), e1 = expf(l1 - mx);
    float s = 1.0f / (e0 + e1);
    out[(size_t)n * 2 + 0] = e0 * s;
    out[(size_t)n * 2 + 1] = e1 * s;
  }
}

extern "C" void kernel_launch(void* const* d_in, const int* in_sizes, int n_in,
                              void* d_out, int out_size, void* d_ws, size_t ws_size,
                              hipStream_t stream) {
  const float* feat = (const float*)d_in[0];
  const int* eidx = (const int*)d_in[1];
  const int* src = eidx;
  const int* dst = eidx + N_EDGES;
  const float* W1l = (const float*)d_in[2];
  const float* b1  = (const float*)d_in[3];
  const float* W1r = (const float*)d_in[4];
  const float* W2l = (const float*)d_in[5];
  const float* b2  = (const float*)d_in[6];
  const float* W2r = (const float*)d_in[7];
  const float* Wfc = (const float*)d_in[8];
  const float* bfc = (const float*)d_in[9];
  float* out = (float*)d_out;

  // workspace layout (all 16B aligned)
  int* deg       = (int*)d_ws;
  int* rowStart  = deg + 50176;
  int* cursor    = rowStart + 50176;
  int* blockSums = cursor + 50176;
  int* col       = blockSums + 256;                        // 600064 (64 slack)
  unsigned short* featb = (unsigned short*)(col + 600064); // 50000*128
  unsigned short* agg1b = featb + 6400000;                 // 50000*128
  unsigned short* h1b   = agg1b + 6400000;                 // 50000*256
  unsigned short* Tb    = h1b + 12800000;                  // 50000*256
  unsigned short* Wc1   = Tb + 12800000;                   // 256*256
  unsigned short* Wc2   = Wc1 + 65536;                     // 256*256

  k_zero_deg<<<NB_SCAN, 256, 0, stream>>>(deg);
  k_count<<<(N_EDGES + 255) / 256, 256, 0, stream>>>(dst, deg);
  k_scanA<<<NB_SCAN, 256, 0, stream>>>(deg, rowStart, blockSums);
  k_scanB<<<1, 256, 0, stream>>>(blockSums, NB_SCAN);
  k_scanC<<<NB_SCAN, 256, 0, stream>>>(rowStart, blockSums, cursor);
  k_fill<<<(N_EDGES + 255) / 256, 256, 0, stream>>>(src, dst, cursor, col);

  k_cvt<<<(3200000 + 255) / 256, 256, 0, stream>>>(feat, featb, 3200000);
  k_cvtw1<<<256, 256, 0, stream>>>(W1l, W1r, Wc1);
  k_cvtw2<<<256, 256, 0, stream>>>(W2l, W2r, Wc2);

  k_agg1<<<N_NODES / 4, 256, 0, stream>>>(featb, rowStart, deg, col, agg1b);
  k_gemm<true><<<(N_NODES + 127) / 128, 256, 0, stream>>>(agg1b, featb, 128, Wc1, b1, h1b);
  k_gemm<false><<<(N_NODES + 127) / 128, 256, 0, stream>>>(h1b, h1b + 128, 256, Wc2, nullptr, Tb);
  k_final<<<N_NODES / 4, 256, 0, stream>>>(Tb, rowStart, deg, col, b2, Wfc, bfc, out);
}

// Round 4
// 273.943 us; speedup vs baseline: 1.8955x; 1.0866x over previous
//
#include <hip/hip_runtime.h>
#include <math.h>

#define N_NODES  50000
#define N_EDGES  600000
#define NB_SCAN  ((N_NODES + 255) / 256)   // 196

typedef __attribute__((ext_vector_type(8))) short bf16x8;
typedef __attribute__((ext_vector_type(4))) float f32x4;
typedef unsigned int uint32;

__device__ __forceinline__ unsigned short f2bf(float x) {
  uint32 u = __builtin_bit_cast(uint32, x);
  u += 0x7FFFu + ((u >> 16) & 1u);   // round-to-nearest-even
  return (unsigned short)(u >> 16);
}
__device__ __forceinline__ float bf2f(uint32 lo16) {
  return __builtin_bit_cast(float, lo16 << 16);
}
__device__ __forceinline__ uint32 pack2(float a, float b) {
  return (uint32)f2bf(a) | ((uint32)f2bf(b) << 16);
}

// ---------------- fused prep: cvt feat, cvt W1, cvt W2, zero deg + col slack ----------------
#define PREP_FEAT_BLOCKS 12500   // 3.2M uint32 / 256
#define PREP_W_BLOCKS    256     // 65536 / 256
__global__ void k_prep(const float* __restrict__ feat, unsigned short* __restrict__ featb,
                       const float* __restrict__ W1l, const float* __restrict__ W1r,
                       unsigned short* __restrict__ Wc1,
                       const float* __restrict__ W2l, const float* __restrict__ W2r,
                       unsigned short* __restrict__ Wc2,
                       int* __restrict__ deg, int* __restrict__ colSlack) {
  const int bid = blockIdx.x, t = threadIdx.x;
  if (bid < PREP_FEAT_BLOCKS) {
    int i = bid * 256 + t;
    float2 v = ((const float2*)feat)[i];
    ((uint32*)featb)[i] = pack2(v.x, v.y);
  } else if (bid < PREP_FEAT_BLOCKS + PREP_W_BLOCKS) {
    int id = (bid - PREP_FEAT_BLOCKS) * 256 + t;
    int n = id >> 8, k = id & 255;
    float v = (k < 128) ? W1l[n * 128 + k] : W1r[n * 128 + (k - 128)];
    Wc1[id] = f2bf(v);
  } else if (bid < PREP_FEAT_BLOCKS + 2 * PREP_W_BLOCKS) {
    int id = (bid - PREP_FEAT_BLOCKS - PREP_W_BLOCKS) * 256 + t;
    int n = id >> 8, k = id & 255;
    float v = (n < 128) ? W2l[n * 256 + k] : W2r[(n - 128) * 256 + k];
    Wc2[id] = f2bf(v);
  } else {
    int i = (bid - PREP_FEAT_BLOCKS - 2 * PREP_W_BLOCKS) * 256 + t;
    if (i < N_NODES) deg[i] = 0;
    if (i < 64) colSlack[i] = 0;
  }
}
#define PREP_BLOCKS (PREP_FEAT_BLOCKS + 2 * PREP_W_BLOCKS + NB_SCAN)

// ---------------- CSR build ----------------
__global__ void k_count(const int* __restrict__ dst, int* __restrict__ deg) {
  int i = blockIdx.x * 256 + threadIdx.x;
  if (i < N_EDGES) atomicAdd(&deg[dst[i]], 1);
}

__global__ void k_scanA(const int* __restrict__ deg, int* __restrict__ partial,
                        int* __restrict__ blockSums) {
  __shared__ int s[256];
  int t = threadIdx.x;
  int i = blockIdx.x * 256 + t;
  int v = (i < N_NODES) ? deg[i] : 0;
  s[t] = v; __syncthreads();
  for (int off = 1; off < 256; off <<= 1) {
    int y = (t >= off) ? s[t - off] : 0;
    __syncthreads();
    s[t] += y;
    __syncthreads();
  }
  if (i < N_NODES) partial[i] = s[t] - v;
  if (t == 255) blockSums[blockIdx.x] = s[255];
}

__global__ void k_scanB(int* __restrict__ blockSums, int nb) {
  __shared__ int s[256];
  int t = threadIdx.x;
  int v = (t < nb) ? blockSums[t] : 0;
  s[t] = v; __syncthreads();
  for (int off = 1; off < 256; off <<= 1) {
    int y = (t >= off) ? s[t - off] : 0;
    __syncthreads();
    s[t] += y;
    __syncthreads();
  }
  if (t < nb) blockSums[t] = s[t] - v;
}

__global__ void k_scanC(int* __restrict__ rowStart, const int* __restrict__ blockSums,
                        int* __restrict__ cursor) {
  int i = blockIdx.x * 256 + threadIdx.x;
  if (i < N_NODES) {
    int r = rowStart[i] + blockSums[blockIdx.x];
    rowStart[i] = r;
    cursor[i] = r;
  }
}

__global__ void k_fill(const int* __restrict__ src, const int* __restrict__ dst,
                       int* __restrict__ cursor, int* __restrict__ col) {
  int i = blockIdx.x * 256 + threadIdx.x;
  if (i < N_EDGES) {
    int p = atomicAdd(&cursor[dst[i]], 1);
    col[p] = src[i];
  }
}

// ---------------- 4-deep gather-mean core ----------------
// STRIDE = row stride in uint32. col has 64 zeroed slack ints past N_EDGES, so
// prefetching indices up to rs+dg+3 is safe; slack index 0 loads row 0 but is
// never accumulated (wave-uniform remainder branches).
template<int STRIDE>
__device__ __forceinline__ void gather4(const uint32* __restrict__ base,
                                        const int* __restrict__ col,
                                        int rs, int dg, int lane,
                                        float& s0, float& s1) {
  int i0 = col[rs + 0], i1 = col[rs + 1], i2 = col[rs + 2], i3 = col[rs + 3];
  float a0 = 0.f, a1 = 0.f, b0 = 0.f, b1 = 0.f;
  float c0 = 0.f, c1 = 0.f, d0 = 0.f, d1 = 0.f;
  int j = 0;
  for (; j + 4 <= dg; j += 4) {
    uint32 v0 = base[(size_t)i0 * STRIDE + lane];
    uint32 v1 = base[(size_t)i1 * STRIDE + lane];
    uint32 v2 = base[(size_t)i2 * STRIDE + lane];
    uint32 v3 = base[(size_t)i3 * STRIDE + lane];
    i0 = col[rs + j + 4]; i1 = col[rs + j + 5];
    i2 = col[rs + j + 6]; i3 = col[rs + j + 7];
    a0 += bf2f(v0 & 0xffffu); a1 += bf2f(v0 >> 16);
    b0 += bf2f(v1 & 0xffffu); b1 += bf2f(v1 >> 16);
    c0 += bf2f(v2 & 0xffffu); c1 += bf2f(v2 >> 16);
    d0 += bf2f(v3 & 0xffffu); d1 += bf2f(v3 >> 16);
  }
  if (j < dg)     { uint32 v = base[(size_t)i0 * STRIDE + lane]; a0 += bf2f(v & 0xffffu); a1 += bf2f(v >> 16); }
  if (j + 1 < dg) { uint32 v = base[(size_t)i1 * STRIDE + lane]; b0 += bf2f(v & 0xffffu); b1 += bf2f(v >> 16); }
  if (j + 2 < dg) { uint32 v = base[(size_t)i2 * STRIDE + lane]; c0 += bf2f(v & 0xffffu); c1 += bf2f(v >> 16); }
  s0 = (a0 + b0) + (c0 + d0);
  s1 = (a1 + b1) + (c1 + d1);
}

// ---------------- layer-1 aggregation: one wave per node over featb ----------------
__global__ void k_agg1(const unsigned short* __restrict__ x, const int* __restrict__ rowStart,
                       const int* __restrict__ deg, const int* __restrict__ col,
                       unsigned short* __restrict__ agg) {
  int lane = threadIdx.x & 63;
  int n = blockIdx.x * 4 + (threadIdx.x >> 6);
  int rs = rowStart[n], dg = deg[n];
  float s0, s1;
  gather4<64>((const uint32*)x, col, rs, dg, lane, s0, s1);
  float inv = 1.0f / fmaxf((float)dg, 1.0f);
  ((uint32*)agg)[(size_t)n * 64 + lane] = pack2(s0 * inv, s1 * inv);
}

// ---------------- MFMA GEMM with LDS-staged W ----------------
// Y(bf16)[M][256] = [A0|A1](bf16, K=256) @ W(bf16,[256][256])^T
// block = 256 thr = 4 waves; wave = 32 rows x 256 cols; W staged in 2 64KB halves
// via global_load_lds; LDS chunk-transposed [kchunk][n] so B-frag ds_read_b128 is
// bank-conflict-free.
template<bool NORM>
__global__ __launch_bounds__(256, 2) void k_gemm(
    const unsigned short* __restrict__ A0, const unsigned short* __restrict__ A1,
    int lda, const unsigned short* __restrict__ W, const float* __restrict__ bias,
    unsigned short* __restrict__ Y) {
  __shared__ unsigned short Ws[128 * 256];  // 64 KB
  const int t = threadIdx.x;
  const int lane = t & 63, w = t >> 6;
  const int mi = lane & 15, quad = lane >> 4;
  const int m0 = blockIdx.x * 128 + w * 32;
  f32x4 acc[2][16];
  #pragma unroll
  for (int rt = 0; rt < 2; ++rt)
    #pragma unroll
    for (int a = 0; a < 16; ++a) acc[rt][a] = (f32x4){0.f, 0.f, 0.f, 0.f};

  for (int half = 0; half < 2; ++half) {
    {
      const unsigned short* gb = W + (size_t)half * 128 * 256;
      #pragma unroll
      for (int i = 0; i < 16; ++i) {
        int chunk0 = (w * 16 + i) * 64;          // wave-uniform
        int j = chunk0 >> 7;
        int n0 = chunk0 & 127;
        const unsigned short* gp = gb + (size_t)(n0 + lane) * 256 + j * 8;
        unsigned short* lp = Ws + (size_t)chunk0 * 8;
        __builtin_amdgcn_global_load_lds(
            (const __attribute__((address_space(1))) void*)gp,
            (__attribute__((address_space(3))) void*)lp, 16, 0, 0);
      }
    }
    __syncthreads();
    #pragma unroll
    for (int c = 0; c < 8; ++c) {
      const unsigned short* ap = (c < 4) ? (A0 + c * 32) : (A1 + (c - 4) * 32);
      bf16x8 a0 = *(const bf16x8*)(ap + (size_t)(m0 + mi) * lda + quad * 8);
      bf16x8 a1 = *(const bf16x8*)(ap + (size_t)(m0 + 16 + mi) * lda + quad * 8);
      #pragma unroll
      for (int nt = 0; nt < 8; ++nt) {
        bf16x8 b = *(const bf16x8*)(Ws + ((size_t)(c * 4 + quad) * 128 + nt * 16 + mi) * 8);
        int a = half * 8 + nt;
        acc[0][a] = __builtin_amdgcn_mfma_f32_16x16x32_bf16(a0, b, acc[0][a], 0, 0, 0);
        acc[1][a] = __builtin_amdgcn_mfma_f32_16x16x32_bf16(a1, b, acc[1][a], 0, 0, 0);
      }
    }
    __syncthreads();
  }

  if (NORM) {
    float ss[2][4] = {};
    #pragma unroll
    for (int a = 0; a < 16; ++a) {
      float bv = bias[a * 16 + mi];
      #pragma unroll
      for (int rt = 0; rt < 2; ++rt)
        #pragma unroll
        for (int r = 0; r < 4; ++r) {
          float v = acc[rt][a][r] + bv;
          acc[rt][a][r] = v;
          ss[rt][r] += v * v;
        }
    }
    #pragma unroll
    for (int rt = 0; rt < 2; ++rt)
      #pragma unroll
      for (int r = 0; r < 4; ++r) {
        float s = ss[rt][r];
        s += __shfl_xor(s, 1, 64);
        s += __shfl_xor(s, 2, 64);
        s += __shfl_xor(s, 4, 64);
        s += __shfl_xor(s, 8, 64);
        ss[rt][r] = 1.0f / fmaxf(sqrtf(s), 1e-12f);
      }
    #pragma unroll
    for (int a = 0; a < 16; ++a)
      #pragma unroll
      for (int rt = 0; rt < 2; ++rt)
        #pragma unroll
        for (int r = 0; r < 4; ++r)
          acc[rt][a][r] = fmaxf(acc[rt][a][r] * ss[rt][r], 0.f);
  }

  if (m0 + 32 <= N_NODES) {
    #pragma unroll
    for (int rt = 0; rt < 2; ++rt)
      #pragma unroll
      for (int r = 0; r < 4; ++r) {
        size_t row = m0 + rt * 16 + quad * 4 + r;
        #pragma unroll
        for (int a = 0; a < 16; ++a)
          Y[row * 256 + a * 16 + mi] = f2bf(acc[rt][a][r]);
      }
  } else {
    #pragma unroll
    for (int rt = 0; rt < 2; ++rt)
      #pragma unroll
      for (int r = 0; r < 4; ++r) {
        int row = m0 + rt * 16 + quad * 4 + r;
        if (row < N_NODES) {
          #pragma unroll
          for (int a = 0; a < 16; ++a)
            Y[(size_t)row * 256 + a * 16 + mi] = f2bf(acc[rt][a][r]);
        }
      }
  }
}

// ---------------- fused layer-2 tail ----------------
// T[n][0:128]=Tl (aggregated), T[n][128:256]=Tr. one wave per node.
__global__ void k_final(const unsigned short* __restrict__ T, const int* __restrict__ rowStart,
                        const int* __restrict__ deg, const int* __restrict__ col,
                        const float* __restrict__ b2, const float* __restrict__ Wfc,
                        const float* __restrict__ bfc, float* __restrict__ out) {
  int lane = threadIdx.x & 63;
  int n = blockIdx.x * 4 + (threadIdx.x >> 6);
  int rs = rowStart[n], dg = deg[n];
  const uint32* base = (const uint32*)T;   // row stride 128 uints; Tl first 64, Tr next 64
  float s0, s1;
  gather4<128>(base, col, rs, dg, lane, s0, s1);
  float inv = 1.0f / fmaxf((float)dg, 1.0f);
  uint32 tv = base[(size_t)n * 128 + 64 + lane];
  int d = lane * 2;
  float h0 = s0 * inv + bf2f(tv & 0xffffu) + b2[d];
  float h1 = s1 * inv + bf2f(tv >> 16) + b2[d + 1];
  float ss = h0 * h0 + h1 * h1;
  #pragma unroll
  for (int m = 1; m < 64; m <<= 1) ss += __shfl_xor(ss, m, 64);
  float iv = 1.0f / fmaxf(sqrtf(ss), 1e-12f);
  h0 *= iv; h1 *= iv;
  float p0 = h0 * Wfc[d] + h1 * Wfc[d + 1];
  float p1 = h0 * Wfc[128 + d] + h1 * Wfc[128 + d + 1];
  #pragma unroll
  for (int m = 1; m < 64; m <<= 1) {
    p0 += __shfl_xor(p0, m, 64);
    p1 += __shfl_xor(p1, m, 64);
  }
  if (lane == 0) {
    float l0 = p0 + bfc[0], l1 = p1 + bfc[1];
    float mx = fmaxf(l0, l1);
    float e0 = expf(l0 - mx), e1 = expf(l1 - mx);
    float s = 1.0f / (e0 + e1);
    out[(size_t)n * 2 + 0] = e0 * s;
    out[(size_t)n * 2 + 1] = e1 * s;
  }
}

extern "C" void kernel_launch(void* const* d_in, const int* in_sizes, int n_in,
                              void* d_out, int out_size, void* d_ws, size_t ws_size,
                              hipStream_t stream) {
  const float* feat = (const float*)d_in[0];
  const int* eidx = (const int*)d_in[1];
  const int* src = eidx;
  const int* dst = eidx + N_EDGES;
  const float* W1l = (const float*)d_in[2];
  const float* b1  = (const float*)d_in[3];
  const float* W1r = (const float*)d_in[4];
  const float* W2l = (const float*)d_in[5];
  const float* b2  = (const float*)d_in[6];
  const float* W2r = (const float*)d_in[7];
  const float* Wfc = (const float*)d_in[8];
  const float* bfc = (const float*)d_in[9];
  float* out = (float*)d_out;

  // workspace layout (all 16B aligned)
  int* deg       = (int*)d_ws;
  int* rowStart  = deg + 50176;
  int* cursor    = rowStart + 50176;
  int* blockSums = cursor + 50176;
  int* col       = blockSums + 256;                        // 600064 (64 slack, zeroed by k_prep)
  unsigned short* featb = (unsigned short*)(col + 600064); // 50000*128
  unsigned short* agg1b = featb + 6400000;                 // 50000*128
  unsigned short* h1b   = agg1b + 6400000;                 // 50000*256
  unsigned short* Tb    = h1b + 12800000;                  // 50000*256
  unsigned short* Wc1   = Tb + 12800000;                   // 256*256
  unsigned short* Wc2   = Wc1 + 65536;                     // 256*256

  k_prep<<<PREP_BLOCKS, 256, 0, stream>>>(feat, featb, W1l, W1r, Wc1,
                                          W2l, W2r, Wc2, deg, col + N_EDGES);
  k_count<<<(N_EDGES + 255) / 256, 256, 0, stream>>>(dst, deg);
  k_scanA<<<NB_SCAN, 256, 0, stream>>>(deg, rowStart, blockSums);
  k_scanB<<<1, 256, 0, stream>>>(blockSums, NB_SCAN);
  k_scanC<<<NB_SCAN, 256, 0, stream>>>(rowStart, blockSums, cursor);
  k_fill<<<(N_EDGES + 255) / 256, 256, 0, stream>>>(src, dst, cursor, col);

  k_agg1<<<N_NODES / 4, 256, 0, stream>>>(featb, rowStart, deg, col, agg1b);
  k_gemm<true><<<(N_NODES + 127) / 128, 256, 0, stream>>>(agg1b, featb, 128, Wc1, b1, h1b);
  k_gemm<false><<<(N_NODES + 127) / 128, 256, 0, stream>>>(h1b, h1b + 128, 256, Wc2, nullptr, Tb);
  k_final<<<N_NODES / 4, 256, 0, stream>>>(Tb, rowStart, deg, col, b2, Wfc, bfc, out);
}

// Round 5
// 270.342 us; speedup vs baseline: 1.9207x; 1.0133x over previous
//
#include <hip/hip_runtime.h>
#include <math.h>

#define N_NODES  50000
#define N_EDGES  600000
#define NB_SCAN  ((N_NODES + 255) / 256)   // 196

typedef __attribute__((ext_vector_type(8))) short bf16x8;
typedef __attribute__((ext_vector_type(4))) float f32x4;
typedef unsigned int uint32;

__device__ __forceinline__ unsigned short f2bf(float x) {
  uint32 u = __builtin_bit_cast(uint32, x);
  u += 0x7FFFu + ((u >> 16) & 1u);   // round-to-nearest-even
  return (unsigned short)(u >> 16);
}
__device__ __forceinline__ float bf2f(uint32 lo16) {
  return __builtin_bit_cast(float, lo16 << 16);
}
__device__ __forceinline__ uint32 pack2(float a, float b) {
  return (uint32)f2bf(a) | ((uint32)f2bf(b) << 16);
}

// ---------------- fused prep: cvt feat, cvt W1, cvt W2, zero deg + col slack ----------------
#define PREP_FEAT_BLOCKS 12500   // 3.2M uint32 / 256
#define PREP_W_BLOCKS    256     // 65536 / 256
__global__ void k_prep(const float* __restrict__ feat, unsigned short* __restrict__ featb,
                       const float* __restrict__ W1l, const float* __restrict__ W1r,
                       unsigned short* __restrict__ Wc1,
                       const float* __restrict__ W2l, const float* __restrict__ W2r,
                       unsigned short* __restrict__ Wc2,
                       int* __restrict__ deg, int* __restrict__ colSlack) {
  const int bid = blockIdx.x, t = threadIdx.x;
  if (bid < PREP_FEAT_BLOCKS) {
    int i = bid * 256 + t;
    float2 v = ((const float2*)feat)[i];
    ((uint32*)featb)[i] = pack2(v.x, v.y);
  } else if (bid < PREP_FEAT_BLOCKS + PREP_W_BLOCKS) {
    int id = (bid - PREP_FEAT_BLOCKS) * 256 + t;
    int n = id >> 8, k = id & 255;
    float v = (k < 128) ? W1l[n * 128 + k] : W1r[n * 128 + (k - 128)];
    Wc1[id] = f2bf(v);
  } else if (bid < PREP_FEAT_BLOCKS + 2 * PREP_W_BLOCKS) {
    int id = (bid - PREP_FEAT_BLOCKS - PREP_W_BLOCKS) * 256 + t;
    int n = id >> 8, k = id & 255;
    float v = (n < 128) ? W2l[n * 256 + k] : W2r[(n - 128) * 256 + k];
    Wc2[id] = f2bf(v);
  } else {
    int i = (bid - PREP_FEAT_BLOCKS - 2 * PREP_W_BLOCKS) * 256 + t;
    if (i < N_NODES) deg[i] = 0;
    if (i < 64) colSlack[i] = 0;
  }
}
#define PREP_BLOCKS (PREP_FEAT_BLOCKS + 2 * PREP_W_BLOCKS + NB_SCAN)

// ---------------- CSR build ----------------
__global__ void k_count(const int* __restrict__ dst, int* __restrict__ deg) {
  int i = blockIdx.x * 256 + threadIdx.x;
  if (i < N_EDGES) atomicAdd(&deg[dst[i]], 1);
}

__global__ void k_scanA(const int* __restrict__ deg, int* __restrict__ partial,
                        int* __restrict__ blockSums) {
  __shared__ int s[256];
  int t = threadIdx.x;
  int i = blockIdx.x * 256 + t;
  int v = (i < N_NODES) ? deg[i] : 0;
  s[t] = v; __syncthreads();
  for (int off = 1; off < 256; off <<= 1) {
    int y = (t >= off) ? s[t - off] : 0;
    __syncthreads();
    s[t] += y;
    __syncthreads();
  }
  if (i < N_NODES) partial[i] = s[t] - v;
  if (t == 255) blockSums[blockIdx.x] = s[255];
}

__global__ void k_scanB(int* __restrict__ blockSums, int nb) {
  __shared__ int s[256];
  int t = threadIdx.x;
  int v = (t < nb) ? blockSums[t] : 0;
  s[t] = v; __syncthreads();
  for (int off = 1; off < 256; off <<= 1) {
    int y = (t >= off) ? s[t - off] : 0;
    __syncthreads();
    s[t] += y;
    __syncthreads();
  }
  if (t < nb) blockSums[t] = s[t] - v;
}

__global__ void k_scanC(int* __restrict__ rowStart, const int* __restrict__ blockSums,
                        int* __restrict__ cursor) {
  int i = blockIdx.x * 256 + threadIdx.x;
  if (i < N_NODES) {
    int r = rowStart[i] + blockSums[blockIdx.x];
    rowStart[i] = r;
    cursor[i] = r;
  }
}

__global__ void k_fill(const int* __restrict__ src, const int* __restrict__ dst,
                       int* __restrict__ cursor, int* __restrict__ col) {
  int i = blockIdx.x * 256 + threadIdx.x;
  if (i < N_EDGES) {
    int p = atomicAdd(&cursor[dst[i]], 1);
    col[p] = src[i];
  }
}

// ---------------- 8-deep gather-mean core ----------------
// STRIDE in uint32. col has 64 zeroed slack ints past N_EDGES (k_prep), so index
// prefetch up to rs+dg+7 is safe; slack index 0 is never used as a row load
// except under a false guard.
template<int STRIDE>
__device__ __forceinline__ void gather8(const uint32* __restrict__ base,
                                        const int* __restrict__ col,
                                        int rs, int dg, int lane,
                                        float& s0, float& s1) {
  int idx[8];
  #pragma unroll
  for (int q = 0; q < 8; ++q) idx[q] = col[rs + q];
  float a0[8] = {}, a1[8] = {};
  int j = 0;
  for (; j + 8 <= dg; j += 8) {
    uint32 v[8];
    #pragma unroll
    for (int q = 0; q < 8; ++q) v[q] = base[(size_t)idx[q] * STRIDE + lane];
    #pragma unroll
    for (int q = 0; q < 8; ++q) idx[q] = col[rs + j + 8 + q];
    #pragma unroll
    for (int q = 0; q < 8; ++q) {
      a0[q] += bf2f(v[q] & 0xffffu);
      a1[q] += bf2f(v[q] >> 16);
    }
  }
  #pragma unroll
  for (int q = 0; q < 7; ++q) {
    if (j + q < dg) {
      uint32 v = base[(size_t)idx[q] * STRIDE + lane];
      a0[q] += bf2f(v & 0xffffu);
      a1[q] += bf2f(v >> 16);
    }
  }
  s0 = ((a0[0] + a0[1]) + (a0[2] + a0[3])) + ((a0[4] + a0[5]) + (a0[6] + a0[7]));
  s1 = ((a1[0] + a1[1]) + (a1[2] + a1[3])) + ((a1[4] + a1[5]) + (a1[6] + a1[7]));
}

// ---------------- layer-1 aggregation: one wave per node over featb ----------------
__global__ void k_agg1(const unsigned short* __restrict__ x, const int* __restrict__ rowStart,
                       const int* __restrict__ deg, const int* __restrict__ col,
                       unsigned short* __restrict__ agg) {
  int lane = threadIdx.x & 63;
  int n = blockIdx.x * 4 + (threadIdx.x >> 6);
  int rs = rowStart[n], dg = deg[n];
  float s0, s1;
  gather8<64>((const uint32*)x, col, rs, dg, lane, s0, s1);
  float inv = 1.0f / fmaxf((float)dg, 1.0f);
  ((uint32*)agg)[(size_t)n * 64 + lane] = pack2(s0 * inv, s1 * inv);
}

// ---------------- MFMA GEMM with LDS-staged W ----------------
// [Yl|Yr](bf16, each row-stride ldy) = [A0|A1](bf16, K=256) @ W(bf16,[256][256])^T
// block = 256 thr = 4 waves; wave = 32 rows x 256 cols; W staged in 2 64KB halves
// via global_load_lds; LDS chunk-transposed [kchunk][n] so B-frag ds_read_b128 is
// bank-conflict-free. Output cols 0..127 -> Yl, 128..255 -> Yr.
template<bool NORM>
__global__ __launch_bounds__(256, 2) void k_gemm(
    const unsigned short* __restrict__ A0, const unsigned short* __restrict__ A1,
    int lda, const unsigned short* __restrict__ W, const float* __restrict__ bias,
    unsigned short* __restrict__ Yl, unsigned short* __restrict__ Yr, int ldy) {
  __shared__ unsigned short Ws[128 * 256];  // 64 KB
  const int t = threadIdx.x;
  const int lane = t & 63, w = t >> 6;
  const int mi = lane & 15, quad = lane >> 4;
  const int m0 = blockIdx.x * 128 + w * 32;
  f32x4 acc[2][16];
  #pragma unroll
  for (int rt = 0; rt < 2; ++rt)
    #pragma unroll
    for (int a = 0; a < 16; ++a) acc[rt][a] = (f32x4){0.f, 0.f, 0.f, 0.f};

  for (int half = 0; half < 2; ++half) {
    {
      const unsigned short* gb = W + (size_t)half * 128 * 256;
      #pragma unroll
      for (int i = 0; i < 16; ++i) {
        int chunk0 = (w * 16 + i) * 64;          // wave-uniform
        int j = chunk0 >> 7;
        int n0 = chunk0 & 127;
        const unsigned short* gp = gb + (size_t)(n0 + lane) * 256 + j * 8;
        unsigned short* lp = Ws + (size_t)chunk0 * 8;
        __builtin_amdgcn_global_load_lds(
            (const __attribute__((address_space(1))) void*)gp,
            (__attribute__((address_space(3))) void*)lp, 16, 0, 0);
      }
    }
    __syncthreads();
    #pragma unroll
    for (int c = 0; c < 8; ++c) {
      const unsigned short* ap = (c < 4) ? (A0 + c * 32) : (A1 + (c - 4) * 32);
      bf16x8 a0 = *(const bf16x8*)(ap + (size_t)(m0 + mi) * lda + quad * 8);
      bf16x8 a1 = *(const bf16x8*)(ap + (size_t)(m0 + 16 + mi) * lda + quad * 8);
      #pragma unroll
      for (int nt = 0; nt < 8; ++nt) {
        bf16x8 b = *(const bf16x8*)(Ws + ((size_t)(c * 4 + quad) * 128 + nt * 16 + mi) * 8);
        int a = half * 8 + nt;
        acc[0][a] = __builtin_amdgcn_mfma_f32_16x16x32_bf16(a0, b, acc[0][a], 0, 0, 0);
        acc[1][a] = __builtin_amdgcn_mfma_f32_16x16x32_bf16(a1, b, acc[1][a], 0, 0, 0);
      }
    }
    __syncthreads();
  }

  if (NORM) {
    float ss[2][4] = {};
    #pragma unroll
    for (int a = 0; a < 16; ++a) {
      float bv = bias[a * 16 + mi];
      #pragma unroll
      for (int rt = 0; rt < 2; ++rt)
        #pragma unroll
        for (int r = 0; r < 4; ++r) {
          float v = acc[rt][a][r] + bv;
          acc[rt][a][r] = v;
          ss[rt][r] += v * v;
        }
    }
    #pragma unroll
    for (int rt = 0; rt < 2; ++rt)
      #pragma unroll
      for (int r = 0; r < 4; ++r) {
        float s = ss[rt][r];
        s += __shfl_xor(s, 1, 64);
        s += __shfl_xor(s, 2, 64);
        s += __shfl_xor(s, 4, 64);
        s += __shfl_xor(s, 8, 64);
        ss[rt][r] = 1.0f / fmaxf(sqrtf(s), 1e-12f);
      }
    #pragma unroll
    for (int a = 0; a < 16; ++a)
      #pragma unroll
      for (int rt = 0; rt < 2; ++rt)
        #pragma unroll
        for (int r = 0; r < 4; ++r)
          acc[rt][a][r] = fmaxf(acc[rt][a][r] * ss[rt][r], 0.f);
  }

  #pragma unroll
  for (int rt = 0; rt < 2; ++rt)
    #pragma unroll
    for (int r = 0; r < 4; ++r) {
      int row = m0 + rt * 16 + quad * 4 + r;
      if (row < N_NODES) {
        #pragma unroll
        for (int a = 0; a < 16; ++a) {
          unsigned short* Y = (a < 8) ? Yl : Yr;
          Y[(size_t)row * ldy + (a & 7) * 16 + mi] = f2bf(acc[rt][a][r]);
        }
      }
    }
}

// ---------------- fused layer-2 tail ----------------
// Tl[n][0:128] aggregated over neighbors; Tr[n][0:128] self term. one wave per node.
__global__ void k_final(const unsigned short* __restrict__ Tl, const unsigned short* __restrict__ Tr,
                        const int* __restrict__ rowStart, const int* __restrict__ deg,
                        const int* __restrict__ col,
                        const float* __restrict__ b2, const float* __restrict__ Wfc,
                        const float* __restrict__ bfc, float* __restrict__ out) {
  int lane = threadIdx.x & 63;
  int n = blockIdx.x * 4 + (threadIdx.x >> 6);
  int rs = rowStart[n], dg = deg[n];
  float s0, s1;
  gather8<64>((const uint32*)Tl, col, rs, dg, lane, s0, s1);
  float inv = 1.0f / fmaxf((float)dg, 1.0f);
  uint32 tv = ((const uint32*)Tr)[(size_t)n * 64 + lane];
  int d = lane * 2;
  float h0 = s0 * inv + bf2f(tv & 0xffffu) + b2[d];
  float h1 = s1 * inv + bf2f(tv >> 16) + b2[d + 1];
  float ss = h0 * h0 + h1 * h1;
  #pragma unroll
  for (int m = 1; m < 64; m <<= 1) ss += __shfl_xor(ss, m, 64);
  float iv = 1.0f / fmaxf(sqrtf(ss), 1e-12f);
  h0 *= iv; h1 *= iv;
  float p0 = h0 * Wfc[d] + h1 * Wfc[d + 1];
  float p1 = h0 * Wfc[128 + d] + h1 * Wfc[128 + d + 1];
  #pragma unroll
  for (int m = 1; m < 64; m <<= 1) {
    p0 += __shfl_xor(p0, m, 64);
    p1 += __shfl_xor(p1, m, 64);
  }
  if (lane == 0) {
    float l0 = p0 + bfc[0], l1 = p1 + bfc[1];
    float mx = fmaxf(l0, l1);
    float e0 = expf(l0 - mx), e1 = expf(l1 - mx);
    float s = 1.0f / (e0 + e1);
    out[(size_t)n * 2 + 0] = e0 * s;
    out[(size_t)n * 2 + 1] = e1 * s;
  }
}

extern "C" void kernel_launch(void* const* d_in, const int* in_sizes, int n_in,
                              void* d_out, int out_size, void* d_ws, size_t ws_size,
                              hipStream_t stream) {
  const float* feat = (const float*)d_in[0];
  const int* eidx = (const int*)d_in[1];
  const int* src = eidx;
  const int* dst = eidx + N_EDGES;
  const float* W1l = (const float*)d_in[2];
  const float* b1  = (const float*)d_in[3];
  const float* W1r = (const float*)d_in[4];
  const float* W2l = (const float*)d_in[5];
  const float* b2  = (const float*)d_in[6];
  const float* W2r = (const float*)d_in[7];
  const float* Wfc = (const float*)d_in[8];
  const float* bfc = (const float*)d_in[9];
  float* out = (float*)d_out;

  // workspace layout (all 16B aligned)
  int* deg       = (int*)d_ws;
  int* rowStart  = deg + 50176;
  int* cursor    = rowStart + 50176;
  int* blockSums = cursor + 50176;
  int* col       = blockSums + 256;                        // 600064 (64 slack, zeroed by k_prep)
  unsigned short* featb = (unsigned short*)(col + 600064); // 50000*128
  unsigned short* agg1b = featb + 6400000;                 // 50000*128
  unsigned short* h1b   = agg1b + 6400000;                 // 50000*256
  unsigned short* Tlb   = h1b + 12800000;                  // 50000*128
  unsigned short* Trb   = Tlb + 6400000;                   // 50000*128
  unsigned short* Wc1   = Trb + 6400000;                   // 256*256
  unsigned short* Wc2   = Wc1 + 65536;                     // 256*256

  k_prep<<<PREP_BLOCKS, 256, 0, stream>>>(feat, featb, W1l, W1r, Wc1,
                                          W2l, W2r, Wc2, deg, col + N_EDGES);
  k_count<<<(N_EDGES + 255) / 256, 256, 0, stream>>>(dst, deg);
  k_scanA<<<NB_SCAN, 256, 0, stream>>>(deg, rowStart, blockSums);
  k_scanB<<<1, 256, 0, stream>>>(blockSums, NB_SCAN);
  k_scanC<<<NB_SCAN, 256, 0, stream>>>(rowStart, blockSums, cursor);
  k_fill<<<(N_EDGES + 255) / 256, 256, 0, stream>>>(src, dst, cursor, col);

  k_agg1<<<N_NODES / 4, 256, 0, stream>>>(featb, rowStart, deg, col, agg1b);
  // layer 1: Yl/Yr are halves of the same h1 buffer (row stride 256)
  k_gemm<true><<<(N_NODES + 127) / 128, 256, 0, stream>>>(
      agg1b, featb, 128, Wc1, b1, h1b, h1b + 128, 256);
  // layer 2: split outputs into contiguous Tl / Tr (row stride 128)
  k_gemm<false><<<(N_NODES + 127) / 128, 256, 0, stream>>>(
      h1b, h1b + 128, 256, Wc2, nullptr, Tlb, Trb, 128);
  k_final<<<N_NODES / 4, 256, 0, stream>>>(Tlb, Trb, rowStart, deg, col, b2, Wfc, bfc, out);
}